// Round 2
// baseline (1786.535 us; speedup 1.0000x reference)
//
#include <hip/hip_runtime.h>
#include <hip/hip_bf16.h>

typedef unsigned int u32;
typedef unsigned short u16;

// ---------- helpers ----------
__device__ __forceinline__ float2 up2(u32 u) {
    return make_float2(__uint_as_float(u << 16), __uint_as_float(u & 0xffff0000u));
}
__device__ __forceinline__ u16 f2bf(float f) {  // round-to-nearest-even
    u32 x = __float_as_uint(f);
    return (u16)((x + 0x7fffu + ((x >> 16) & 1u)) >> 16);
}
__device__ __forceinline__ u32 pack2(float a, float b) {
    return (u32)f2bf(a) | ((u32)f2bf(b) << 16);
}
__device__ __forceinline__ void cvt8(uint4 w, float* o) {
    float2 a = up2(w.x), b = up2(w.y), c = up2(w.z), d = up2(w.w);
    o[0]=a.x; o[1]=a.y; o[2]=b.x; o[3]=b.y; o[4]=c.x; o[5]=c.y; o[6]=d.x; o[7]=d.y;
}
__device__ __forceinline__ float wred_sum(float v) {
    #pragma unroll
    for (int o = 32; o; o >>= 1) v += __shfl_xor(v, o);
    return v;
}
__device__ __forceinline__ float wred_max(float v) {
    #pragma unroll
    for (int o = 32; o; o >>= 1) v = fmaxf(v, __shfl_xor(v, o));
    return v;
}
__device__ __forceinline__ float gelu_f(float x) {
    return 0.5f * x * (1.0f + erff(x * 0.70710678118654752f));
}

// ---------------- Kernel 1: window attention (LN1 + QKV + attn + proj + reverse) ----------------
// Global I/O: float32.  LDS staging: bf16 (threshold 8.4e-2 tolerates it).
// LDS layout (bytes):
//   s_x   bf16 [49][136] @ 0      (13328)
//   s_out bf16 [49][136] @ 13328  (13328) -> 26656
//   s_qkv bf16 [49][104] @ 26656  (10192) -> 36848
//   s_S   f32  [49][52]  @ 36848  (10192)            (union w/ s_wt)
//   s_wt  bf16 [96][136] @ 36848  (26112) -> 62960
//   s_pwt bf16 [128][136]@ 26656  (34816) -> 61472   (union w/ s_qkv+s_S, proj phase only)
#define K2_SMEM 62960

__global__ __launch_bounds__(256)
void swin_attn(const float* __restrict__ x, const float* __restrict__ qkv_w, const float* __restrict__ qkv_b,
               const float* __restrict__ proj_w, const float* __restrict__ proj_b, const float* __restrict__ rel_t,
               const float* __restrict__ ln1s, const float* __restrict__ ln1b, float* __restrict__ xo)
{
    __shared__ uint4 smem4[K2_SMEM / 16];
    char* smem = (char*)smem4;
    u16*   s_x   = (u16*)(smem + 0);
    u16*   s_out = (u16*)(smem + 13328);
    u16*   s_qkv = (u16*)(smem + 26656);
    float* s_S   = (float*)(smem + 36848);
    u16*   s_wt  = (u16*)(smem + 36848);
    u16*   s_pwt = (u16*)(smem + 26656);

    const int tid  = threadIdx.x;
    const int lane = tid & 63;
    const int wvid = tid >> 6;
    const int win  = blockIdx.x;
    const int b    = win >> 6;
    const int wh   = (win >> 3) & 7;
    const int wwi  = win & 7;

    // ---- LN1 + window gather (wave per token) ----
    {
        float2 g2  = ((const float2*)ln1s)[lane];
        float2 bb2 = ((const float2*)ln1b)[lane];
        for (int i = wvid; i < 49; i += 4) {
            int r = i / 7, cc = i - r * 7;
            const float2* row = (const float2*)(x + (((size_t)(b * 3136 + (wh * 7 + r) * 56 + (wwi * 7 + cc))) << 7));
            float2 v = row[lane];
            float s  = wred_sum(v.x + v.y);
            float sq = wred_sum(v.x * v.x + v.y * v.y);
            float m   = s * (1.0f / 128.0f);
            float var = sq * (1.0f / 128.0f) - m * m;
            float rs  = rsqrtf(var + 1e-5f);
            ((u32*)s_x)[i * 68 + lane] = pack2((v.x - m) * rs * g2.x + bb2.x,
                                               (v.y - m) * rs * g2.y + bb2.y);
        }
    }
    __syncthreads();

    const int n4 = tid >> 2;   // 0..63 (used when tid<196 -> 0..48)
    const int q4 = tid & 3;    // 0..3

    for (int h = 0; h < 4; ++h) {
        // ---- stage qkv_w slice, transposed: s_wt[j][c] ----
        for (int e = tid; e < 12288; e += 256) {
            int c = e / 96, j = e - c * 96;
            int gcol = ((j >> 5) << 7) + (h << 5) + (j & 31);
            s_wt[j * 136 + c] = f2bf(qkv_w[c * 384 + gcol]);
        }
        __syncthreads();

        // ---- q/k/v for this head: thread (n, jgroup of 24) ----
        if (tid < 196) {
            float acc[24];
            #pragma unroll
            for (int u = 0; u < 24; ++u) {
                int j = q4 * 24 + u;
                int gcol = ((j >> 5) << 7) + (h << 5) + (j & 31);
                acc[u] = qkv_b[gcol];
            }
            for (int c = 0; c < 128; c += 8) {
                float xv[8]; cvt8(*(const uint4*)(s_x + n4 * 136 + c), xv);
                #pragma unroll
                for (int u = 0; u < 24; ++u) {
                    float wv8[8]; cvt8(*(const uint4*)(s_wt + (q4 * 24 + u) * 136 + c), wv8);
                    #pragma unroll
                    for (int r = 0; r < 8; ++r) acc[u] = fmaf(xv[r], wv8[r], acc[u]);
                }
            }
            #pragma unroll
            for (int u = 0; u < 24; u += 2) {
                int j = q4 * 24 + u;
                ((u32*)s_qkv)[(n4 * 104 + j) >> 1] = pack2(acc[u], acc[u + 1]);
            }
        }
        __syncthreads();

        // ---- S = q k^T * scale + bias ----
        for (int idx = tid; idx < 2401; idx += 256) {
            int i = idx / 49, j = idx - i * 49;
            float acc = 0.f;
            #pragma unroll
            for (int dd = 0; dd < 32; dd += 8) {
                float qv[8], kv[8];
                cvt8(*(const uint4*)(s_qkv + i * 104 + dd), qv);
                cvt8(*(const uint4*)(s_qkv + j * 104 + 32 + dd), kv);
                #pragma unroll
                for (int r = 0; r < 8; ++r) acc = fmaf(qv[r], kv[r], acc);
            }
            int iy = i / 7, ix = i - iy * 7, jy = j / 7, jx = j - jy * 7;
            int tix = (iy - jy + 6) * 13 + (ix - jx + 6);
            s_S[i * 52 + j] = acc * 0.17677669529663687f + rel_t[tix * 4 + h];
        }
        __syncthreads();

        // ---- softmax (wave per row) ----
        for (int i = wvid; i < 49; i += 4) {
            float v = (lane < 49) ? s_S[i * 52 + lane] : -3.4e38f;
            float m = wred_max(v);
            float e = (lane < 49) ? __expf(v - m) : 0.f;
            float s = wred_sum(e);
            if (lane < 49) s_S[i * 52 + lane] = e / s;
        }
        __syncthreads();

        // ---- out = P @ v : thread (i, 8-dd group) ----
        if (tid < 196) {
            float acc[8] = {0, 0, 0, 0, 0, 0, 0, 0};
            for (int j = 0; j < 49; ++j) {
                float p = s_S[n4 * 52 + j];
                float vv[8]; cvt8(*(const uint4*)(s_qkv + j * 104 + 64 + q4 * 8), vv);
                #pragma unroll
                for (int r = 0; r < 8; ++r) acc[r] = fmaf(p, vv[r], acc[r]);
            }
            #pragma unroll
            for (int r = 0; r < 8; r += 2)
                ((u32*)s_out)[(n4 * 136 + h * 32 + q4 * 8 + r) >> 1] = pack2(acc[r], acc[r + 1]);
        }
        __syncthreads();
    }

    // ---- stage proj_w transposed: s_pwt[oc][c] ----
    for (int e = tid; e < 16384; e += 256) {
        int c = e >> 7, oc = e & 127;
        s_pwt[oc * 136 + c] = f2bf(proj_w[e]);
    }
    __syncthreads();

    // ---- proj + window reverse scatter (f32 out) ----
    if (tid < 196) {
        float acc[32];
        #pragma unroll
        for (int u = 0; u < 32; ++u) acc[u] = proj_b[q4 * 32 + u];
        for (int c = 0; c < 128; c += 8) {
            float xv[8]; cvt8(*(const uint4*)(s_out + n4 * 136 + c), xv);
            #pragma unroll
            for (int u = 0; u < 32; ++u) {
                float wv8[8]; cvt8(*(const uint4*)(s_pwt + (q4 * 32 + u) * 136 + c), wv8);
                #pragma unroll
                for (int r = 0; r < 8; ++r) acc[u] = fmaf(xv[r], wv8[r], acc[u]);
            }
        }
        int r = n4 / 7, cc = n4 - r * 7;
        float* orow = xo + (((size_t)(b * 3136 + (wh * 7 + r) * 56 + (wwi * 7 + cc))) << 7) + q4 * 32;
        #pragma unroll
        for (int u = 0; u < 32; u += 4)
            *(float4*)(orow + u) = make_float4(acc[u], acc[u + 1], acc[u + 2], acc[u + 3]);
    }
}

// ---------------- Kernel 2: LN2 + MLP (GELU) + residual (IN PLACE on xo==out) ----------------
// LDS: s_n bf16 [64][136] @0 (17408); s_h bf16 [64][136] @17408; s_wt bf16 [128][136] @34816 -> 69632
#define K3_SMEM 69632

__global__ __launch_bounds__(256)
void swin_mlp(const float* xo, const float* __restrict__ ln2s, const float* __restrict__ ln2b,
              const float* __restrict__ w1, const float* __restrict__ b1,
              const float* __restrict__ w2, const float* __restrict__ b2, float* out)
{
    __shared__ uint4 smem4[K3_SMEM / 16];
    char* smem = (char*)smem4;
    u16* s_n  = (u16*)(smem + 0);
    u16* s_h  = (u16*)(smem + 17408);
    u16* s_wt = (u16*)(smem + 34816);

    const int tid  = threadIdx.x;
    const int lane = tid & 63;
    const int wvid = tid >> 6;
    const size_t t0 = (size_t)blockIdx.x * 64;

    // ---- LN2 (wave per token) ----
    {
        float2 g2  = ((const float2*)ln2s)[lane];
        float2 bb2 = ((const float2*)ln2b)[lane];
        for (int t = wvid; t < 64; t += 4) {
            const float2* row = (const float2*)(xo + ((t0 + t) << 7));
            float2 v = row[lane];
            float s  = wred_sum(v.x + v.y);
            float sq = wred_sum(v.x * v.x + v.y * v.y);
            float m   = s * (1.0f / 128.0f);
            float var = sq * (1.0f / 128.0f) - m * m;
            float rs  = rsqrtf(var + 1e-5f);
            ((u32*)s_n)[t * 68 + lane] = pack2((v.x - m) * rs * g2.x + bb2.x,
                                               (v.y - m) * rs * g2.y + bb2.y);
        }
    }
    __syncthreads();

    const int tt = tid >> 2;   // token in tile: 0..63
    const int og = tid & 3;    // 32-col group
    float acc[32];
    #pragma unroll
    for (int u = 0; u < 32; ++u) acc[u] = b2[og * 32 + u];

    for (int fb = 0; fb < 512; fb += 128) {
        // stage w1 chunk transposed: s_wt[f][c]
        for (int e = tid; e < 16384; e += 256) {
            int c = e >> 7, f = e & 127;
            s_wt[f * 136 + c] = f2bf(w1[c * 512 + fb + f]);
        }
        __syncthreads();

        // hidden chunk: h[t][f] = gelu(xn2 . w1 + b1)
        {
            float hacc[32];
            #pragma unroll
            for (int u = 0; u < 32; ++u) hacc[u] = b1[fb + og * 32 + u];
            for (int c = 0; c < 128; c += 8) {
                float xv[8]; cvt8(*(const uint4*)(s_n + tt * 136 + c), xv);
                #pragma unroll
                for (int u = 0; u < 32; ++u) {
                    float wv8[8]; cvt8(*(const uint4*)(s_wt + (og * 32 + u) * 136 + c), wv8);
                    #pragma unroll
                    for (int r = 0; r < 8; ++r) hacc[u] = fmaf(xv[r], wv8[r], hacc[u]);
                }
            }
            #pragma unroll
            for (int u = 0; u < 32; u += 2) {
                ((u32*)s_h)[(tt * 136 + og * 32 + u) >> 1] = pack2(gelu_f(hacc[u]), gelu_f(hacc[u + 1]));
            }
        }
        __syncthreads();  // w1t reads + s_h writes done

        // stage w2 chunk transposed: s_wt[oc][f]
        for (int e = tid; e < 16384; e += 256) {
            int f = e >> 7, oc = e & 127;
            s_wt[oc * 136 + f] = f2bf(w2[(fb + f) * 128 + oc]);
        }
        __syncthreads();

        // acc[oc] += h . w2
        for (int f = 0; f < 128; f += 8) {
            float hv[8]; cvt8(*(const uint4*)(s_h + tt * 136 + f), hv);
            #pragma unroll
            for (int u = 0; u < 32; ++u) {
                float wv8[8]; cvt8(*(const uint4*)(s_wt + (og * 32 + u) * 136 + f), wv8);
                #pragma unroll
                for (int r = 0; r < 8; ++r) acc[u] = fmaf(hv[r], wv8[r], acc[u]);
            }
        }
        __syncthreads();  // before next chunk clobbers s_wt / s_h
    }

    // ---- residual + store (in place; each thread touches only its own slice) ----
    const float* xrow = xo + ((t0 + tt) << 7) + og * 32;
    float* orow = out + ((t0 + tt) << 7) + og * 32;
    #pragma unroll
    for (int u = 0; u < 32; u += 4) {
        float4 xr = *(const float4*)(xrow + u);
        *(float4*)(orow + u) = make_float4(acc[u] + xr.x, acc[u + 1] + xr.y,
                                           acc[u + 2] + xr.z, acc[u + 3] + xr.w);
    }
}

extern "C" void kernel_launch(void* const* d_in, const int* in_sizes, int n_in,
                              void* d_out, int out_size, void* d_ws, size_t ws_size,
                              hipStream_t stream) {
    (void)in_sizes; (void)n_in; (void)out_size; (void)d_ws; (void)ws_size;
    const float* x      = (const float*)d_in[0];
    // d_in[1], d_in[2] are H, W scalars (56, 56) - hardcoded
    const float* qkv_w  = (const float*)d_in[3];
    const float* qkv_b  = (const float*)d_in[4];
    const float* proj_w = (const float*)d_in[5];
    const float* proj_b = (const float*)d_in[6];
    const float* rel_t  = (const float*)d_in[7];
    const float* ln1s   = (const float*)d_in[8];
    const float* ln1b   = (const float*)d_in[9];
    const float* ln2s   = (const float*)d_in[10];
    const float* ln2b   = (const float*)d_in[11];
    const float* w1     = (const float*)d_in[12];
    const float* b1     = (const float*)d_in[13];
    const float* w2     = (const float*)d_in[14];
    const float* b2     = (const float*)d_in[15];

    float* out = (float*)d_out;   // also used as the attention-output buffer (in-place MLP)

    swin_attn<<<2048, 256, 0, stream>>>(x, qkv_w, qkv_b, proj_w, proj_b, rel_t, ln1s, ln1b, out);
    swin_mlp<<<1568, 256, 0, stream>>>(out, ln2s, ln2b, w1, b1, w2, b2, out);
}

// Round 3
// 994.027 us; speedup vs baseline: 1.7973x; 1.7973x over previous
//
#include <hip/hip_runtime.h>
#include <hip/hip_bf16.h>

typedef unsigned int u32;
typedef unsigned short u16;

using bf16x8 = __attribute__((ext_vector_type(8))) short;  // 8 bf16 = 4 VGPRs
using f32x4  = __attribute__((ext_vector_type(4))) float;  // 4 fp32

// ---------- helpers ----------
__device__ __forceinline__ float2 up2(u32 u) {
    return make_float2(__uint_as_float(u << 16), __uint_as_float(u & 0xffff0000u));
}
__device__ __forceinline__ u16 f2bf(float f) {  // round-to-nearest-even
    u32 x = __float_as_uint(f);
    return (u16)((x + 0x7fffu + ((x >> 16) & 1u)) >> 16);
}
__device__ __forceinline__ u32 pack2(float a, float b) {
    return (u32)f2bf(a) | ((u32)f2bf(b) << 16);
}
__device__ __forceinline__ void cvt8(uint4 w, float* o) {
    float2 a = up2(w.x), b = up2(w.y), c = up2(w.z), d = up2(w.w);
    o[0]=a.x; o[1]=a.y; o[2]=b.x; o[3]=b.y; o[4]=c.x; o[5]=c.y; o[6]=d.x; o[7]=d.y;
}
__device__ __forceinline__ float wred_sum(float v) {
    #pragma unroll
    for (int o = 32; o; o >>= 1) v += __shfl_xor(v, o);
    return v;
}
__device__ __forceinline__ float wred_max(float v) {
    #pragma unroll
    for (int o = 32; o; o >>= 1) v = fmaxf(v, __shfl_xor(v, o));
    return v;
}
__device__ __forceinline__ float gelu_f(float x) {
    return 0.5f * x * (1.0f + erff(x * 0.70710678118654752f));
}

// ---------------- Kernel 1: window attention (LN1 + QKV + attn + proj + reverse) ----------------
// (unchanged from round 1 — passed; MFMA-ize next round)
#define K2_SMEM 62960

__global__ __launch_bounds__(256)
void swin_attn(const float* __restrict__ x, const float* __restrict__ qkv_w, const float* __restrict__ qkv_b,
               const float* __restrict__ proj_w, const float* __restrict__ proj_b, const float* __restrict__ rel_t,
               const float* __restrict__ ln1s, const float* __restrict__ ln1b, float* __restrict__ xo)
{
    __shared__ uint4 smem4[K2_SMEM / 16];
    char* smem = (char*)smem4;
    u16*   s_x   = (u16*)(smem + 0);
    u16*   s_out = (u16*)(smem + 13328);
    u16*   s_qkv = (u16*)(smem + 26656);
    float* s_S   = (float*)(smem + 36848);
    u16*   s_wt  = (u16*)(smem + 36848);
    u16*   s_pwt = (u16*)(smem + 26656);

    const int tid  = threadIdx.x;
    const int lane = tid & 63;
    const int wvid = tid >> 6;
    const int win  = blockIdx.x;
    const int b    = win >> 6;
    const int wh   = (win >> 3) & 7;
    const int wwi  = win & 7;

    {
        float2 g2  = ((const float2*)ln1s)[lane];
        float2 bb2 = ((const float2*)ln1b)[lane];
        for (int i = wvid; i < 49; i += 4) {
            int r = i / 7, cc = i - r * 7;
            const float2* row = (const float2*)(x + (((size_t)(b * 3136 + (wh * 7 + r) * 56 + (wwi * 7 + cc))) << 7));
            float2 v = row[lane];
            float s  = wred_sum(v.x + v.y);
            float sq = wred_sum(v.x * v.x + v.y * v.y);
            float m   = s * (1.0f / 128.0f);
            float var = sq * (1.0f / 128.0f) - m * m;
            float rs  = rsqrtf(var + 1e-5f);
            ((u32*)s_x)[i * 68 + lane] = pack2((v.x - m) * rs * g2.x + bb2.x,
                                               (v.y - m) * rs * g2.y + bb2.y);
        }
    }
    __syncthreads();

    const int n4 = tid >> 2;
    const int q4 = tid & 3;

    for (int h = 0; h < 4; ++h) {
        for (int e = tid; e < 12288; e += 256) {
            int c = e / 96, j = e - c * 96;
            int gcol = ((j >> 5) << 7) + (h << 5) + (j & 31);
            s_wt[j * 136 + c] = f2bf(qkv_w[c * 384 + gcol]);
        }
        __syncthreads();

        if (tid < 196) {
            float acc[24];
            #pragma unroll
            for (int u = 0; u < 24; ++u) {
                int j = q4 * 24 + u;
                int gcol = ((j >> 5) << 7) + (h << 5) + (j & 31);
                acc[u] = qkv_b[gcol];
            }
            for (int c = 0; c < 128; c += 8) {
                float xv[8]; cvt8(*(const uint4*)(s_x + n4 * 136 + c), xv);
                #pragma unroll
                for (int u = 0; u < 24; ++u) {
                    float wv8[8]; cvt8(*(const uint4*)(s_wt + (q4 * 24 + u) * 136 + c), wv8);
                    #pragma unroll
                    for (int r = 0; r < 8; ++r) acc[u] = fmaf(xv[r], wv8[r], acc[u]);
                }
            }
            #pragma unroll
            for (int u = 0; u < 24; u += 2) {
                int j = q4 * 24 + u;
                ((u32*)s_qkv)[(n4 * 104 + j) >> 1] = pack2(acc[u], acc[u + 1]);
            }
        }
        __syncthreads();

        for (int idx = tid; idx < 2401; idx += 256) {
            int i = idx / 49, j = idx - i * 49;
            float acc = 0.f;
            #pragma unroll
            for (int dd = 0; dd < 32; dd += 8) {
                float qv[8], kv[8];
                cvt8(*(const uint4*)(s_qkv + i * 104 + dd), qv);
                cvt8(*(const uint4*)(s_qkv + j * 104 + 32 + dd), kv);
                #pragma unroll
                for (int r = 0; r < 8; ++r) acc = fmaf(qv[r], kv[r], acc);
            }
            int iy = i / 7, ix = i - iy * 7, jy = j / 7, jx = j - jy * 7;
            int tix = (iy - jy + 6) * 13 + (ix - jx + 6);
            s_S[i * 52 + j] = acc * 0.17677669529663687f + rel_t[tix * 4 + h];
        }
        __syncthreads();

        for (int i = wvid; i < 49; i += 4) {
            float v = (lane < 49) ? s_S[i * 52 + lane] : -3.4e38f;
            float m = wred_max(v);
            float e = (lane < 49) ? __expf(v - m) : 0.f;
            float s = wred_sum(e);
            if (lane < 49) s_S[i * 52 + lane] = e / s;
        }
        __syncthreads();

        if (tid < 196) {
            float acc[8] = {0, 0, 0, 0, 0, 0, 0, 0};
            for (int j = 0; j < 49; ++j) {
                float p = s_S[n4 * 52 + j];
                float vv[8]; cvt8(*(const uint4*)(s_qkv + j * 104 + 64 + q4 * 8), vv);
                #pragma unroll
                for (int r = 0; r < 8; ++r) acc[r] = fmaf(p, vv[r], acc[r]);
            }
            #pragma unroll
            for (int r = 0; r < 8; r += 2)
                ((u32*)s_out)[(n4 * 136 + h * 32 + q4 * 8 + r) >> 1] = pack2(acc[r], acc[r + 1]);
        }
        __syncthreads();
    }

    for (int e = tid; e < 16384; e += 256) {
        int c = e >> 7, oc = e & 127;
        s_pwt[oc * 136 + c] = f2bf(proj_w[e]);
    }
    __syncthreads();

    if (tid < 196) {
        float acc[32];
        #pragma unroll
        for (int u = 0; u < 32; ++u) acc[u] = proj_b[q4 * 32 + u];
        for (int c = 0; c < 128; c += 8) {
            float xv[8]; cvt8(*(const uint4*)(s_out + n4 * 136 + c), xv);
            #pragma unroll
            for (int u = 0; u < 32; ++u) {
                float wv8[8]; cvt8(*(const uint4*)(s_pwt + (q4 * 32 + u) * 136 + c), wv8);
                #pragma unroll
                for (int r = 0; r < 8; ++r) acc[u] = fmaf(xv[r], wv8[r], acc[u]);
            }
        }
        int r = n4 / 7, cc = n4 - r * 7;
        float* orow = xo + (((size_t)(b * 3136 + (wh * 7 + r) * 56 + (wwi * 7 + cc))) << 7) + q4 * 32;
        #pragma unroll
        for (int u = 0; u < 32; u += 4)
            *(float4*)(orow + u) = make_float4(acc[u], acc[u + 1], acc[u + 2], acc[u + 3]);
    }
}

// ---------------- Kernel 2: LN2 + MLP (GELU) + residual — MFMA version, in place ----------------
// 64 tokens/block, 256 threads = 4 waves in a 2x2 grid; each wave owns a 32x64 output stripe.
// LDS: s_x bf16[64][136] @0 (17408); s_h bf16[64][136] @17408; s_w bf16[128][136] @34816 -> 69632
#define MLP_SMEM 69632

__global__ __launch_bounds__(256)
void swin_mlp_mfma(const float* xo, const float* __restrict__ ln2s, const float* __restrict__ ln2b,
                   const float* __restrict__ w1, const float* __restrict__ b1,
                   const float* __restrict__ w2, const float* __restrict__ b2, float* out)
{
    __shared__ uint4 smem4[MLP_SMEM / 16];
    char* smem = (char*)smem4;
    u16* s_x = (u16*)(smem + 0);       // LN2(x) tile   [64 tok][136]
    u16* s_h = (u16*)(smem + 17408);   // hidden chunk  [64 tok][136] (cols = f local 0..127)
    u16* s_w = (u16*)(smem + 34816);   // weight chunk  [128][136] (transposed)

    const int tid  = threadIdx.x;
    const int lane = tid & 63;
    const int wv   = tid >> 6;
    const size_t t0 = (size_t)blockIdx.x * 64;

    // ---- LN2 (wave per token) ----
    {
        float2 g2  = ((const float2*)ln2s)[lane];
        float2 bb2 = ((const float2*)ln2b)[lane];
        for (int t = wv; t < 64; t += 4) {
            const float2* row = (const float2*)(xo + ((t0 + t) << 7));
            float2 v = row[lane];
            float s  = wred_sum(v.x + v.y);
            float sq = wred_sum(v.x * v.x + v.y * v.y);
            float m   = s * (1.0f / 128.0f);
            float var = sq * (1.0f / 128.0f) - m * m;
            float rs  = rsqrtf(var + 1e-5f);
            ((u32*)s_x)[t * 68 + lane] = pack2((v.x - m) * rs * g2.x + bb2.x,
                                               (v.y - m) * rs * g2.y + bb2.y);
        }
    }
    __syncthreads();

    const int wr = wv >> 1;     // 0..1 : 32-row stripe
    const int wc = wv & 1;      // 0..1 : 64-col stripe
    const int lr = lane & 15;   // fragment row/col index
    const int lg = lane >> 4;   // k-group 0..3

    f32x4 acc2[2][4];
    #pragma unroll
    for (int m = 0; m < 2; ++m)
        #pragma unroll
        for (int n = 0; n < 4; ++n) acc2[m][n] = (f32x4){0.f, 0.f, 0.f, 0.f};

    float bias2[4];
    #pragma unroll
    for (int n = 0; n < 4; ++n) bias2[n] = b2[wc * 64 + n * 16 + lr];

    for (int fb = 0; fb < 512; fb += 128) {
        // ---- stage w1 chunk transposed: s_w[f][c] = w1[c][fb+f] ----
        for (int e = tid; e < 16384; e += 256) {
            int f = e & 127, c = e >> 7;
            s_w[f * 136 + c] = f2bf(w1[c * 512 + fb + f]);
        }
        __syncthreads();

        // ---- GEMM1: H = s_x @ w1chunk ----
        f32x4 h[2][4];
        #pragma unroll
        for (int m = 0; m < 2; ++m)
            #pragma unroll
            for (int n = 0; n < 4; ++n) h[m][n] = (f32x4){0.f, 0.f, 0.f, 0.f};

        #pragma unroll
        for (int kb = 0; kb < 4; ++kb) {
            bf16x8 a[2], bq[4];
            #pragma unroll
            for (int m = 0; m < 2; ++m)
                a[m] = *(const bf16x8*)(s_x + (wr * 32 + m * 16 + lr) * 136 + kb * 32 + lg * 8);
            #pragma unroll
            for (int n = 0; n < 4; ++n)
                bq[n] = *(const bf16x8*)(s_w + (wc * 64 + n * 16 + lr) * 136 + kb * 32 + lg * 8);
            #pragma unroll
            for (int m = 0; m < 2; ++m)
                #pragma unroll
                for (int n = 0; n < 4; ++n)
                    h[m][n] = __builtin_amdgcn_mfma_f32_16x16x32_bf16(a[m], bq[n], h[m][n], 0, 0, 0);
        }

        // ---- +b1, GELU, write s_h (D layout: row=(lane>>4)*4+j, col=lane&15) ----
        #pragma unroll
        for (int n = 0; n < 4; ++n) {
            float bv = b1[fb + wc * 64 + n * 16 + lr];
            #pragma unroll
            for (int m = 0; m < 2; ++m) {
                #pragma unroll
                for (int j = 0; j < 4; ++j) {
                    int row = wr * 32 + m * 16 + lg * 4 + j;
                    int col = wc * 64 + n * 16 + lr;
                    s_h[row * 136 + col] = f2bf(gelu_f(h[m][n][j] + bv));
                }
            }
        }
        __syncthreads();   // GEMM1's s_w reads + s_h writes complete

        // ---- stage w2 chunk transposed: s_w[c][f] = w2[fb+f][c] ----
        for (int e = tid; e < 16384; e += 256) {
            int c = e & 127, f = e >> 7;
            s_w[c * 136 + f] = f2bf(w2[(size_t)(fb + f) * 128 + c]);
        }
        __syncthreads();

        // ---- GEMM2: acc2 += s_h @ w2chunk ----
        #pragma unroll
        for (int kb = 0; kb < 4; ++kb) {
            bf16x8 a[2], bq[4];
            #pragma unroll
            for (int m = 0; m < 2; ++m)
                a[m] = *(const bf16x8*)(s_h + (wr * 32 + m * 16 + lr) * 136 + kb * 32 + lg * 8);
            #pragma unroll
            for (int n = 0; n < 4; ++n)
                bq[n] = *(const bf16x8*)(s_w + (wc * 64 + n * 16 + lr) * 136 + kb * 32 + lg * 8);
            #pragma unroll
            for (int m = 0; m < 2; ++m)
                #pragma unroll
                for (int n = 0; n < 4; ++n)
                    acc2[m][n] = __builtin_amdgcn_mfma_f32_16x16x32_bf16(a[m], bq[n], acc2[m][n], 0, 0, 0);
        }
        __syncthreads();   // before next chunk clobbers s_w / s_h
    }

    // ---- epilogue: +b2, +residual, in-place store ----
    #pragma unroll
    for (int m = 0; m < 2; ++m) {
        #pragma unroll
        for (int n = 0; n < 4; ++n) {
            #pragma unroll
            for (int j = 0; j < 4; ++j) {
                int row = wr * 32 + m * 16 + lg * 4 + j;
                int col = wc * 64 + n * 16 + lr;
                size_t idx = ((t0 + row) << 7) + col;
                out[idx] = acc2[m][n][j] + bias2[n] + xo[idx];
            }
        }
    }
}

extern "C" void kernel_launch(void* const* d_in, const int* in_sizes, int n_in,
                              void* d_out, int out_size, void* d_ws, size_t ws_size,
                              hipStream_t stream) {
    (void)in_sizes; (void)n_in; (void)out_size; (void)d_ws; (void)ws_size;
    const float* x      = (const float*)d_in[0];
    // d_in[1], d_in[2] are H, W scalars (56, 56) - hardcoded
    const float* qkv_w  = (const float*)d_in[3];
    const float* qkv_b  = (const float*)d_in[4];
    const float* proj_w = (const float*)d_in[5];
    const float* proj_b = (const float*)d_in[6];
    const float* rel_t  = (const float*)d_in[7];
    const float* ln1s   = (const float*)d_in[8];
    const float* ln1b   = (const float*)d_in[9];
    const float* ln2s   = (const float*)d_in[10];
    const float* ln2b   = (const float*)d_in[11];
    const float* w1     = (const float*)d_in[12];
    const float* b1     = (const float*)d_in[13];
    const float* w2     = (const float*)d_in[14];
    const float* b2     = (const float*)d_in[15];

    float* out = (float*)d_out;   // attention output lives here; MLP runs in place

    swin_attn<<<2048, 256, 0, stream>>>(x, qkv_w, qkv_b, proj_w, proj_b, rel_t, ln1s, ln1b, out);
    swin_mlp_mfma<<<1568, 256, 0, stream>>>(out, ln2s, ln2b, w1, b1, w2, b2, out);
}